// Round 2
// baseline (1070.997 us; speedup 1.0000x reference)
//
#include <hip/hip_runtime.h>
#include <math.h>

#define SS 1024           // sequence length
#define DD 1024           // feature dim
#define NB 64             // batch
#define NT 34             // states (33 tags + BOS)
#define MID 511           // fwd computes alpha_MID; bwd computes beta_MID
#define KS 4              // K splits in GEMM
#define KC (DD / KS)      // 256 k per split
#define WPAD 36           // padded W row (16B-aligned LDS rows)

// workspace layout (floats) -- ~280 KB total
#define WS_BOS   0                    // [65536] proj[:,:,33]
#define WS_ALPHA (NB * SS)            // [64*34]
#define WS_BETA  (WS_ALPHA + NB * NT) // [64*34]
#define WS_SCORE (WS_BETA + NB * NT)  // [64]

__device__ __forceinline__ float warp_sum64(float x) {
  #pragma unroll
  for (int off = 32; off > 0; off >>= 1) x += __shfl_down(x, off, 64);
  return x;
}

__device__ __forceinline__ float rfl(float x) {  // broadcast lane0 via SALU
  return __int_as_float(__builtin_amdgcn_readfirstlane(__float_as_int(x)));
}

__device__ __forceinline__ float read_em(const float* __restrict__ logits,
                                         const float* __restrict__ bos,
                                         int b, int t, int j) {
  if (j < 33) return logits[(size_t)(b * SS + t) * 33 + j];
  if (j == 33) return bos[b * SS + t];
  return 0.0f;
}

// ---------------- init: logits/bos <- bias (atomic accumulate targets) -------
__global__ __launch_bounds__(256) void init_bias(const float* __restrict__ bias,
                                                 float* __restrict__ logits,
                                                 float* __restrict__ bos) {
  int idx = blockIdx.x * 256 + threadIdx.x;           // over 65536*34
  int row = idx / NT;
  int j = idx - row * NT;
  if (j < 33) logits[(size_t)row * 33 + j] = bias[j];
  else        bos[row] = bias[33];
}

// ---------------- GEMM: proj += em @ W (K-split, LDS-staged W) ---------------
// grid (256 rowblocks, 4 ksplits) x 256 threads; 1 row per thread per split.
__device__ __forceinline__ void comp16(const float4* __restrict__ Ab,
                                       const float* __restrict__ wl,
                                       int kbase, float* __restrict__ acc) {
  #pragma unroll
  for (int e = 0; e < 4; ++e) {
    float4 a4 = Ab[e];
    #pragma unroll
    for (int u = 0; u < 4; ++u) {
      float av = (u == 0) ? a4.x : (u == 1) ? a4.y : (u == 2) ? a4.z : a4.w;
      const float4* wr = (const float4*)(wl + (kbase + e * 4 + u) * WPAD);
      #pragma unroll
      for (int q = 0; q < 8; ++q) {
        float4 wv = wr[q];
        acc[4*q+0] = fmaf(av, wv.x, acc[4*q+0]);
        acc[4*q+1] = fmaf(av, wv.y, acc[4*q+1]);
        acc[4*q+2] = fmaf(av, wv.z, acc[4*q+2]);
        acc[4*q+3] = fmaf(av, wv.w, acc[4*q+3]);
      }
      float4 wv = wr[8];
      acc[32] = fmaf(av, wv.x, acc[32]);
      acc[33] = fmaf(av, wv.y, acc[33]);
    }
  }
}

__global__ __launch_bounds__(256, 4) void gemm_proj(
    const float* __restrict__ em, const float* __restrict__ W,
    float* __restrict__ logits, float* __restrict__ bos) {
  __shared__ float wl[KC * WPAD];                     // 36 KB
  const int tid = threadIdx.x, rb = blockIdx.x, ks = blockIdx.y;

  const float* Wc = W + ks * KC * NT;                 // contiguous chunk
  for (int idx = tid; idx < KC * NT; idx += 256) {    // coalesced stage
    int k = idx / NT;
    int j = idx - k * NT;
    wl[k * WPAD + j] = Wc[idx];
  }
  __syncthreads();

  const int row = rb * 256 + tid;
  const float4* ar = (const float4*)(em + (size_t)row * DD + ks * KC);
  float acc[NT];
  #pragma unroll
  for (int j = 0; j < NT; ++j) acc[j] = 0.0f;

  float4 A0[4], B0[4];
  #pragma unroll
  for (int e = 0; e < 4; ++e) A0[e] = ar[e];
  #pragma unroll
  for (int e = 0; e < 4; ++e) B0[e] = ar[4 + e];

  #pragma unroll 1
  for (int c = 0; c < KC / 4; c += 8) {               // 8 iterations
    int nc = (c + 8 < KC / 4) ? c + 8 : c;            // last iter: dummy reload
    float4 P[4], Q[4];
    #pragma unroll
    for (int e = 0; e < 4; ++e) P[e] = ar[nc + e];
    comp16(A0, wl, c * 4, acc);
    #pragma unroll
    for (int e = 0; e < 4; ++e) Q[e] = ar[nc + 4 + e];
    comp16(B0, wl, (c + 4) * 4, acc);
    #pragma unroll
    for (int e = 0; e < 4; ++e) { A0[e] = P[e]; B0[e] = Q[e]; }
  }

  float* lrow = logits + (size_t)row * 33;
  #pragma unroll
  for (int j = 0; j < 33; ++j) atomicAdd(lrow + j, acc[j]);
  atomicAdd(bos + row, acc[33]);
}

// ---------------- chains (fwd/bwd) + supervised score ------------------------
// blocks 0..63 fwd, 64..127 bwd, 128..191 score; 64 threads each.
__global__ __launch_bounds__(64) void chains_score(
    const float* __restrict__ logits, const float* __restrict__ bosc,
    const float* __restrict__ T, const float* __restrict__ mask,
    const int* __restrict__ tags, float* __restrict__ alpha_o,
    float* __restrict__ beta_o, float* __restrict__ score_o) {
  __shared__ float sh[64];
  const int blk = blockIdx.x;
  const int lane = threadIdx.x;

  if (blk < 128) {
    const int b = blk & 63;
    const bool fwd = blk < 64;
    const int jc = lane < NT ? lane : NT - 1;
    float eT[NT];

    if (fwd) {
      #pragma unroll
      for (int i = 0; i < NT; ++i) {                  // column jc of exp(T)
        float v = __expf(T[i * NT + jc]);
        eT[i] = (lane < NT) ? v : 0.0f;
      }
      float alpha = -INFINITY;
      if (lane < NT) alpha = T[(NT - 1) * NT + lane] + read_em(logits, bosc, b, 0, lane);
      float eA = (lane < NT) ? read_em(logits, bosc, b, 1, lane) : 0.0f;
      float eB = (lane < NT) ? read_em(logits, bosc, b, 2, lane) : 0.0f;
      float eC = (lane < NT) ? read_em(logits, bosc, b, 3, lane) : 0.0f;
      float mA = mask[b * SS + 1], mB = mask[b * SS + 2], mC = mask[b * SS + 3];
      for (int t = 1; t <= MID; ++t) {
        float e = eA, m = mA;
        eA = eB; eB = eC; mA = mB; mB = mC;
        eC = (lane < NT) ? read_em(logits, bosc, b, t + 3, lane) : 0.0f; // <=514
        mC = mask[b * SS + t + 3];
        if (m > 0.5f) {
          float M = rfl(alpha);                       // lane0 always finite
          float ea = __expf(alpha - M);               // -inf -> 0 (lanes>=NT too)
          sh[lane] = ea;
          const float4* sv = (const float4*)sh;
          float4 v[9];
          #pragma unroll
          for (int q = 0; q < 9; ++q) v[q] = sv[q];
          float s0 = 0.f, s1 = 0.f, s2 = 0.f, s3 = 0.f;
          #pragma unroll
          for (int q = 0; q < 8; ++q) {
            s0 = fmaf(v[q].x, eT[4*q+0], s0);
            s1 = fmaf(v[q].y, eT[4*q+1], s1);
            s2 = fmaf(v[q].z, eT[4*q+2], s2);
            s3 = fmaf(v[q].w, eT[4*q+3], s3);
          }
          s0 = fmaf(v[8].x, eT[32], s0);
          s1 = fmaf(v[8].y, eT[33], s1);
          float s = (s0 + s1) + (s2 + s3);
          alpha = M + __logf(s) + e;                  // lane33: s==0 -> -inf ok
        }
      }
      if (lane < NT) alpha_o[b * NT + lane] = alpha;
    } else {
      #pragma unroll
      for (int i = 0; i < NT; ++i) {                  // row jc of exp(T)
        float v = __expf(T[jc * NT + i]);
        eT[i] = (lane < NT) ? v : 0.0f;
      }
      float beta = (lane < NT) ? 0.0f : -INFINITY;    // junk lanes -> exp()=0
      float eA = (lane < NT) ? read_em(logits, bosc, b, SS - 1, lane) : 0.0f;
      float eB = (lane < NT) ? read_em(logits, bosc, b, SS - 2, lane) : 0.0f;
      float eC = (lane < NT) ? read_em(logits, bosc, b, SS - 3, lane) : 0.0f;
      float mA = mask[b * SS + SS - 1], mB = mask[b * SS + SS - 2], mC = mask[b * SS + SS - 3];
      for (int t = SS - 1; t > MID; --t) {
        float e = eA, m = mA;
        eA = eB; eB = eC; mA = mB; mB = mC;
        eC = (lane < NT) ? read_em(logits, bosc, b, t - 3, lane) : 0.0f; // >=509
        mC = mask[b * SS + t - 3];
        if (m > 0.5f) {
          float g = beta + e;                         // em_t[j] + beta_t[j]
          float M = rfl(g);
          float eg = __expf(g - M);
          sh[lane] = eg;
          const float4* sv = (const float4*)sh;
          float4 v[9];
          #pragma unroll
          for (int q = 0; q < 9; ++q) v[q] = sv[q];
          float s0 = 0.f, s1 = 0.f, s2 = 0.f, s3 = 0.f;
          #pragma unroll
          for (int q = 0; q < 8; ++q) {
            s0 = fmaf(v[q].x, eT[4*q+0], s0);
            s1 = fmaf(v[q].y, eT[4*q+1], s1);
            s2 = fmaf(v[q].z, eT[4*q+2], s2);
            s3 = fmaf(v[q].w, eT[4*q+3], s3);
          }
          s0 = fmaf(v[8].x, eT[32], s0);
          s1 = fmaf(v[8].y, eT[33], s1);
          float s = (s0 + s1) + (s2 + s3);
          beta = M + __logf(s);
        }
      }
      if (lane < NT) beta_o[b * NT + lane] = beta;
    }
  } else {
    // supervised path score, one block per batch, 64 threads
    int b = blk - 128;
    float local = 0.0f;
    for (int t = lane; t < SS; t += 64) {
      if (t == 0) {
        int tg = tags[b * SS];
        local += T[(NT - 1) * NT + tg] + logits[(size_t)(b * SS) * 33 + tg];
      } else {
        int tg = tags[b * SS + t];
        int tp = tags[b * SS + t - 1];
        float m = mask[b * SS + t];
        local += m * (logits[(size_t)(b * SS + t) * 33 + tg] + T[tp * NT + tg]);
      }
    }
    float w = warp_sum64(local);
    if (lane == 0) score_o[b] = w;
  }
}

// ---------------- combine: loss = sum_b (Z_b - score_b) ----------------------
__global__ void combine(const float* __restrict__ alpha, const float* __restrict__ beta,
                        const float* __restrict__ score, float* __restrict__ out) {
  int b = threadIdx.x;  // 64 threads
  float v[NT];
  float M = -INFINITY;
  #pragma unroll
  for (int i = 0; i < NT; ++i) {
    v[i] = alpha[b * NT + i] + beta[b * NT + i];
    M = fmaxf(M, v[i]);
  }
  float s = 0.0f;
  #pragma unroll
  for (int i = 0; i < NT; ++i) s += __expf(v[i] - M);
  float part = (M + __logf(s)) - score[b];
  float tot = warp_sum64(part);
  if (b == 0) out[0] = tot;
}

extern "C" void kernel_launch(void* const* d_in, const int* in_sizes, int n_in,
                              void* d_out, int out_size, void* d_ws, size_t ws_size,
                              hipStream_t stream) {
  const float* em   = (const float*)d_in[0];
  const int*   tags = (const int*)d_in[1];
  const float* mask = (const float*)d_in[2];
  const float* W    = (const float*)d_in[3];
  const float* bias = (const float*)d_in[4];
  const float* T    = (const float*)d_in[5];

  float* out = (float*)d_out;
  float* ws  = (float*)d_ws;
  float* bos   = ws + WS_BOS;
  float* alpha = ws + WS_ALPHA;
  float* beta  = ws + WS_BETA;
  float* score = ws + WS_SCORE;
  float* logits = out + 1;   // d_out = [loss, logits(B,S,33)]

  hipLaunchKernelGGL(init_bias, dim3(NB * SS * NT / 256), dim3(256), 0, stream,
                     bias, logits, bos);
  hipLaunchKernelGGL(gemm_proj, dim3(NB * SS / 256, KS), dim3(256), 0, stream,
                     em, W, logits, bos);
  hipLaunchKernelGGL(chains_score, dim3(192), dim3(64), 0, stream,
                     logits, bos, T, mask, tags, alpha, beta, score);
  hipLaunchKernelGGL(combine, dim3(1), dim3(64), 0, stream,
                     alpha, beta, score, out);
}

// Round 3
// 732.764 us; speedup vs baseline: 1.4616x; 1.4616x over previous
//
#include <hip/hip_runtime.h>
#include <math.h>

#define SS 1024           // sequence length
#define DD 1024           // feature dim
#define NB 64             // batch
#define NT 34             // states (33 tags + BOS)
#define MID 511           // fwd computes alpha_MID; bwd computes beta_MID
#define RB 128            // rows per GEMM block
#define KB 16             // k per chunk per half
#define TSTR 20           // padded k-stride in LDS tile (16B-aligned rows)

// workspace layout (floats)
#define WS_BOS   0                    // [65536] proj[:,:,33]
#define WS_ALPHA (NB * SS)            // [64*34]
#define WS_BETA  (WS_ALPHA + NB * NT) // [64*34]
#define WS_SCORE (WS_BETA + NB * NT)  // [64]

__device__ __forceinline__ float warp_sum64(float x) {
  #pragma unroll
  for (int off = 32; off > 0; off >>= 1) x += __shfl_down(x, off, 64);
  return x;
}

__device__ __forceinline__ float rfl(float x) {  // broadcast lane0 via SALU
  return __int_as_float(__builtin_amdgcn_readfirstlane(__float_as_int(x)));
}

// ---------------- GEMM: proj = em @ W + b ------------------------------------
// 512 blocks x 256 threads. Block = 128 rows; thread (half = tid>>7) covers
// K range half*512..+512 of row (tid&127). em staged coalesced through LDS
// (double-buffered); W read wave-uniform -> s_load (SMEM pipe, K$ broadcast).
// Partial K-halves reduced in LDS; coalesced direct stores. No atomics.
__global__ __launch_bounds__(256, 2) void gemm_proj(
    const float* __restrict__ em, const float* __restrict__ W,
    const float* __restrict__ bias,
    float* __restrict__ logits, float* __restrict__ bos) {
  __shared__ float tile[2][2][RB][TSTR];          // [buf][half][row][k] 40 KB
  const int tid = threadIdx.x;
  const int rb = blockIdx.x;
  const int half = tid >> 7;
  const int r = tid & 127;
  const int khalf = __builtin_amdgcn_readfirstlane(half);  // wave-uniform
  const size_t row0 = (size_t)rb * RB;

  float acc[NT];
  #pragma unroll
  for (int j = 0; j < NT; ++j) acc[j] = (half == 0) ? bias[j] : 0.0f;

  // per-thread staging slots: f = i*256+tid -> (h,row,seg)
  const float* gbase[4];
  float* lb0[4];
  float* lb1[4];
  #pragma unroll
  for (int i = 0; i < 4; ++i) {
    int f = i * 256 + tid;
    int h = f >> 9, rem = f & 511, row = rem >> 2, seg = rem & 3;
    gbase[i] = em + (row0 + row) * DD + h * 512 + seg * 4;
    lb0[i] = &tile[0][h][row][seg * 4];
    lb1[i] = &tile[1][h][row][seg * 4];
  }

  float4 pf[4];
  #pragma unroll
  for (int i = 0; i < 4; ++i) pf[i] = *(const float4*)(gbase[i]);

  for (int c = 0; c < 32; ++c) {                  // 32 chunks of KB=16
    // write prefetched chunk into buf
    if (c & 1) {
      #pragma unroll
      for (int i = 0; i < 4; ++i) *(float4*)lb1[i] = pf[i];
    } else {
      #pragma unroll
      for (int i = 0; i < 4; ++i) *(float4*)lb0[i] = pf[i];
    }
    __syncthreads();
    if (c + 1 < 32) {                             // prefetch next chunk
      #pragma unroll
      for (int i = 0; i < 4; ++i)
        pf[i] = *(const float4*)(gbase[i] + (c + 1) * KB);
    }
    // compute from staged tile
    const float* myrow = &tile[c & 1][half][r][0];
    float a[KB];
    #pragma unroll
    for (int q = 0; q < 4; ++q) {
      float4 v = *(const float4*)(myrow + q * 4);
      a[q*4+0] = v.x; a[q*4+1] = v.y; a[q*4+2] = v.z; a[q*4+3] = v.w;
    }
    const float* wb = W + ((size_t)khalf * 512 + (size_t)c * KB) * NT;
    #pragma unroll
    for (int kk = 0; kk < KB; ++kk) {
      float av = a[kk];
      #pragma unroll
      for (int j = 0; j < NT; ++j)
        acc[j] = fmaf(av, wb[kk * NT + j], acc[j]);  // uniform -> s_load
    }
    __syncthreads();
  }

  // reduce K-halves via LDS, then coalesced store
  float* red = &tile[0][0][0][0];                 // reuse (needs 4352 floats)
  if (half == 1) {
    #pragma unroll
    for (int j = 0; j < NT; ++j) red[r * NT + j] = acc[j];
  }
  __syncthreads();
  if (half == 0) {
    #pragma unroll
    for (int j = 0; j < NT; ++j) red[r * NT + j] += acc[j];
  }
  __syncthreads();
  float* lbase = logits + row0 * 33;
  for (int g = tid; g < RB * 33; g += 256) {
    int row = g / 33, j = g - row * 33;
    lbase[g] = red[row * NT + j];
  }
  if (tid < RB) bos[row0 + tid] = red[tid * NT + 33];
}

// ---------------- chains (fwd/bwd) + supervised score ------------------------
// blocks 0..63 fwd, 64..127 bwd, 128..191 score; 64 threads each.
// State kept as unnormalized p_j with running log-normalizer C (replicated):
// alpha_j = C + log p_j. Per step: share p via LDS, dot with exp(T) (regs),
// renormalize by lane0's s (v_rcp; uniform scale errors cancel through C),
// C += log(r) off critical path. exp(em) pre-staged per 64-step LDS tile.
__global__ __launch_bounds__(64) void chains_score(
    const float* __restrict__ logits, const float* __restrict__ bosc,
    const float* __restrict__ T, const float* __restrict__ mask,
    const int* __restrict__ tags, float* __restrict__ alpha_o,
    float* __restrict__ beta_o, float* __restrict__ score_o) {
  __shared__ float ldsE[64][35];   // [tt][state]: cols 0..32 logits, 33 bos
  __shared__ float ldsM[64];
  __shared__ float shp[64];
  const int blk = blockIdx.x;
  const int lane = threadIdx.x;

  if (blk < 128) {
    const int b = blk & 63;
    const bool fwd = blk < 64;
    const int jc = (lane < NT) ? lane : 0;
    float eT[36];
    #pragma unroll
    for (int i = 0; i < NT; ++i) {
      float tv = fwd ? T[i * NT + jc] : T[jc * NT + i];
      eT[i] = (lane < NT) ? __expf(tv) : 0.0f;
    }
    eT[34] = 0.0f; eT[35] = 0.0f;

    float p, C = 0.0f;
    if (fwd) {
      float em0 = (jc < 33) ? logits[(size_t)(b * SS) * 33 + jc]
                            : bosc[b * SS];
      p = (lane < NT) ? __expf(T[(NT - 1) * NT + jc] + em0) : 0.0f;
    } else {
      p = (lane < NT) ? 1.0f : 0.0f;
    }

    float pe[33], pb, pm;
    // ---- load tile 0 ----
    {
      int t0 = fwd ? 0 : (SS - 1);
      #pragma unroll
      for (int i = 0; i < 33; ++i) {
        int g = lane + i * 64;
        int trow = g / 33, j = g - trow * 33;
        int t = fwd ? (t0 + trow) : (t0 - trow);
        pe[i] = logits[(size_t)(b * SS + t) * 33 + j];
      }
      int tb = fwd ? (t0 + lane) : (t0 - lane);
      pb = bosc[b * SS + tb];
      pm = mask[b * SS + tb];
    }

    for (int c = 0; c < 8; ++c) {
      // ---- expand tile c into LDS (exp of emissions) ----
      #pragma unroll
      for (int i = 0; i < 33; ++i) {
        int g = lane + i * 64;
        int trow = g / 33, j = g - trow * 33;
        ldsE[trow][j] = __expf(pe[i]);
      }
      ldsE[lane][33] = __expf(pb);
      ldsM[lane] = pm;
      // ---- prefetch tile c+1 ----
      if (c < 7) {
        int t0 = fwd ? ((c + 1) * 64) : (SS - 1 - (c + 1) * 64);
        #pragma unroll
        for (int i = 0; i < 33; ++i) {
          int g = lane + i * 64;
          int trow = g / 33, j = g - trow * 33;
          int t = fwd ? (t0 + trow) : (t0 - trow);
          pe[i] = logits[(size_t)(b * SS + t) * 33 + j];
        }
        int tb = fwd ? (t0 + lane) : (t0 - lane);
        pb = bosc[b * SS + tb];
        pm = mask[b * SS + tb];
      }
      // ---- process 64 steps ----
      int ttstart = (fwd && c == 0) ? 1 : 0;
      for (int tt = ttstart; tt < 64; ++tt) {
        float ee = ldsE[tt][jc];
        float m = ldsM[tt];
        float v = fwd ? p : (p * ee);             // bwd: weight by exp(em) first
        shp[lane] = v;
        const float4* sv = (const float4*)shp;
        float s0 = 0.f, s1 = 0.f, s2 = 0.f, s3 = 0.f;
        #pragma unroll
        for (int q = 0; q < 9; ++q) {
          float4 w = sv[q];
          s0 = fmaf(w.x, eT[4*q+0], s0);
          s1 = fmaf(w.y, eT[4*q+1], s1);
          s2 = fmaf(w.z, eT[4*q+2], s2);
          s3 = fmaf(w.w, eT[4*q+3], s3);
        }
        float s = (s0 + s1) + (s2 + s3);
        float rr = rfl(s);                        // lane0's s: always > 0
        float rin = __builtin_amdgcn_rcpf(rr);
        float pn = fwd ? (s * rin * ee) : (s * rin);
        float Cn = C + __logf(rr);                // off critical path
        bool take = (m > 0.5f);
        p = take ? pn : p;
        C = take ? Cn : C;
      }
    }
    float outv = C + __logf(p);                   // p==0 -> -inf (correct)
    if (lane < NT) {
      if (fwd) alpha_o[b * NT + lane] = outv;
      else     beta_o[b * NT + lane] = outv;
    }
  } else {
    // supervised path score, one block per batch, 64 threads
    int b = blk - 128;
    float local = 0.0f;
    for (int t = lane; t < SS; t += 64) {
      if (t == 0) {
        int tg = tags[b * SS];
        local += T[(NT - 1) * NT + tg] + logits[(size_t)(b * SS) * 33 + tg];
      } else {
        int tg = tags[b * SS + t];
        int tp = tags[b * SS + t - 1];
        float m = mask[b * SS + t];
        local += m * (logits[(size_t)(b * SS + t) * 33 + tg] + T[tp * NT + tg]);
      }
    }
    float w = warp_sum64(local);
    if (lane == 0) score_o[b] = w;
  }
}

// ---------------- combine: loss = sum_b (Z_b - score_b) ----------------------
__global__ void combine(const float* __restrict__ alpha, const float* __restrict__ beta,
                        const float* __restrict__ score, float* __restrict__ out) {
  int b = threadIdx.x;  // 64 threads
  float v[NT];
  float M = -INFINITY;
  #pragma unroll
  for (int i = 0; i < NT; ++i) {
    v[i] = alpha[b * NT + i] + beta[b * NT + i];
    M = fmaxf(M, v[i]);
  }
  float s = 0.0f;
  #pragma unroll
  for (int i = 0; i < NT; ++i) s += __expf(v[i] - M);
  float part = (M + __logf(s)) - score[b];
  float tot = warp_sum64(part);
  if (b == 0) out[0] = tot;
}

extern "C" void kernel_launch(void* const* d_in, const int* in_sizes, int n_in,
                              void* d_out, int out_size, void* d_ws, size_t ws_size,
                              hipStream_t stream) {
  const float* em   = (const float*)d_in[0];
  const int*   tags = (const int*)d_in[1];
  const float* mask = (const float*)d_in[2];
  const float* W    = (const float*)d_in[3];
  const float* bias = (const float*)d_in[4];
  const float* T    = (const float*)d_in[5];

  float* out = (float*)d_out;
  float* ws  = (float*)d_ws;
  float* bos   = ws + WS_BOS;
  float* alpha = ws + WS_ALPHA;
  float* beta  = ws + WS_BETA;
  float* score = ws + WS_SCORE;
  float* logits = out + 1;   // d_out = [loss, logits(B,S,33)]

  hipLaunchKernelGGL(gemm_proj, dim3(NB * SS / RB), dim3(256), 0, stream,
                     em, W, bias, logits, bos);
  hipLaunchKernelGGL(chains_score, dim3(192), dim3(64), 0, stream,
                     logits, bos, T, mask, tags, alpha, beta, score);
  hipLaunchKernelGGL(combine, dim3(1), dim3(64), 0, stream,
                     alpha, beta, score, out);
}

// Round 4
// 458.777 us; speedup vs baseline: 2.3345x; 1.5972x over previous
//
#include <hip/hip_runtime.h>
#include <math.h>

#define SS 1024
#define DD 1024
#define NB 64
#define NT 34            // 33 tags + BOS
#define NP 48            // padded state count (3 x 16)
#define NC 16            // time chunks per sequence
#define BOSR 33

typedef __attribute__((ext_vector_type(8))) short bf16x8;
typedef __attribute__((ext_vector_type(4))) float f32x4;

// ---- ws layout (float index) ----
#define WS_BOS   0                              // [65536] proj col 33
#define WS_PMAT  (WS_BOS + NB*SS)               // [64*16*2304] chunk matrices f32
#define WS_CC    (WS_PMAT + NB*NC*NP*NP)        // [1024] chunk log-renorm
#define WS_Z     (WS_CC + NB*NC)                // [64]
#define WS_SC    (WS_Z + NB)                    // [64]
#define WS_BF16  (WS_SC + NB)                   // bf16 region start (ushort*)
// bf16 region (ushort offsets)
#define BW_WT    0                              // Wt[48][1024]: W^T bf16, pad 0
#define BW_ETA   (48*1024)                      // expTA[48][64]: A[m][k]=exp(T[k][m])

__device__ __forceinline__ float warp_sum64(float x) {
  #pragma unroll
  for (int off = 32; off > 0; off >>= 1) x += __shfl_down(x, off, 64);
  return x;
}
__device__ __forceinline__ float rfl(float x) {
  return __int_as_float(__builtin_amdgcn_readfirstlane(__float_as_int(x)));
}
__device__ __forceinline__ unsigned short f2bf(float f) {  // RNE
  unsigned int u = __float_as_uint(f);
  unsigned int r = u + 0x7fffu + ((u >> 16) & 1u);
  return (unsigned short)(r >> 16);
}
__device__ __forceinline__ float bf2f(unsigned short h) {
  return __uint_as_float(((unsigned int)h) << 16);
}

// ---------------- prep: Wt bf16 transpose + expTA ----------------------------
__global__ __launch_bounds__(256) void prep(const float* __restrict__ W,
                                            const float* __restrict__ T,
                                            unsigned short* __restrict__ bw) {
  int idx = blockIdx.x * 256 + threadIdx.x;
  if (idx < 48 * 1024) {                        // Wt[n][k] = W[k][n]
    int n = idx >> 10, k = idx & 1023;
    float v = (n < NT) ? W[k * NT + n] : 0.0f;
    bw[BW_WT + idx] = f2bf(v);
  } else if (idx < 48 * 1024 + 48 * 64) {       // expTA[m][k] = exp(T[k][m])
    int j = idx - 48 * 1024;
    int m = j >> 6, k = j & 63;
    float v = (m < NT && k < NT) ? __expf(T[k * NT + m]) : 0.0f;
    bw[BW_ETA + j] = f2bf(v);
  }
}

// ---------------- GEMM: proj = em @ W + b  (bf16 MFMA, mem-bound) ------------
// 512 blocks x 256 thr; block = 128 rows; wave w: rows w*32..+31 (2 Mtiles),
// 3 Ntiles (48 cols). em f32 -> bf16 staged via double-buffered LDS; W from
// precomputed bf16 Wt (global, L2-resident) prefetched into B-frags.
__global__ __launch_bounds__(256) void gemm_mfma(
    const float* __restrict__ em, const unsigned short* __restrict__ bw,
    const float* __restrict__ bias,
    float* __restrict__ logits, float* __restrict__ bos) {
  __shared__ unsigned short At[2][128][40];     // row stride 40 bf16: 2-way max
  const int tid = threadIdx.x;
  const int lane = tid & 63, wv = tid >> 6;
  const int q = lane >> 4, l15 = lane & 15;
  const size_t row0 = (size_t)blockIdx.x * 128;
  const unsigned short* Wt = bw + BW_WT;
  const float4* g4 = (const float4*)(em + row0 * DD);

  f32x4 acc[2][3];
  f32x4 z4 = {0.f, 0.f, 0.f, 0.f};
  #pragma unroll
  for (int mt = 0; mt < 2; ++mt)
    #pragma unroll
    for (int nt = 0; nt < 3; ++nt) acc[mt][nt] = z4;

  int sr[4], sq[4];
  #pragma unroll
  for (int i = 0; i < 4; ++i) { int s = tid + i * 256; sr[i] = s >> 3; sq[i] = s & 7; }

  float4 pf[4];
  #pragma unroll
  for (int i = 0; i < 4; ++i) pf[i] = g4[sr[i] * 256 + sq[i]];
  bf16x8 Bf[3], Bn[3];
  #pragma unroll
  for (int nt = 0; nt < 3; ++nt)
    Bf[nt] = *(const bf16x8*)(Wt + (nt * 16 + l15) * 1024 + q * 8);

  for (int c = 0; c < 32; ++c) {
    #pragma unroll
    for (int i = 0; i < 4; ++i) {               // stage chunk c (cvt -> b64)
      uint2 pk;
      pk.x = f2bf(pf[i].x) | ((unsigned int)f2bf(pf[i].y) << 16);
      pk.y = f2bf(pf[i].z) | ((unsigned int)f2bf(pf[i].w) << 16);
      *(uint2*)&At[c & 1][sr[i]][sq[i] * 4] = pk;
    }
    int cn = (c + 1 < 32) ? c + 1 : c;          // prefetch chunk c+1
    #pragma unroll
    for (int i = 0; i < 4; ++i) pf[i] = g4[sr[i] * 256 + cn * 8 + sq[i]];
    #pragma unroll
    for (int nt = 0; nt < 3; ++nt)
      Bn[nt] = *(const bf16x8*)(Wt + (nt * 16 + l15) * 1024 + cn * 32 + q * 8);
    __syncthreads();
    bf16x8 Af[2];
    #pragma unroll
    for (int mt = 0; mt < 2; ++mt)
      Af[mt] = *(const bf16x8*)&At[c & 1][wv * 32 + mt * 16 + l15][q * 8];
    #pragma unroll
    for (int mt = 0; mt < 2; ++mt)
      #pragma unroll
      for (int nt = 0; nt < 3; ++nt)
        acc[mt][nt] = __builtin_amdgcn_mfma_f32_16x16x32_bf16(
            Af[mt], Bf[nt], acc[mt][nt], 0, 0, 0);
    #pragma unroll
    for (int nt = 0; nt < 3; ++nt) Bf[nt] = Bn[nt];
  }

  // epilogue: + bias, store cols<33 to logits, col 33 to bos
  #pragma unroll
  for (int nt = 0; nt < 3; ++nt) {
    int col = nt * 16 + l15;
    float bj = (col < NT) ? bias[col] : 0.0f;
    #pragma unroll
    for (int mt = 0; mt < 2; ++mt) {
      #pragma unroll
      for (int r = 0; r < 4; ++r) {
        float v = acc[mt][nt][r] + bj;
        size_t rg = row0 + wv * 32 + mt * 16 + q * 4 + r;
        if (col < 33) logits[rg * 33 + col] = v;
        else if (col == 33) bos[rg] = v;
      }
    }
  }
}

// ---------------- chunk transfer matrices (MFMA) + score ---------------------
// blocks 0..1023: (b,c) chunk matrix, 1 wave. blocks 1024..1087: path score.
// Recurrence (transposed): Q_{t+1} = E^T Q_t, rows scaled by ee, renorm scalar.
// Storage S[n][k] = P[n][k] serves as B-operand (k-contig) AND receives D
// natively (lane col n fixed, 4 contig rows -> k) via ds_write_b64.
__global__ __launch_bounds__(64) void chains_mat(
    const float* __restrict__ logits, const float* __restrict__ bos,
    const unsigned short* __restrict__ bw, const float* __restrict__ mask,
    const float* __restrict__ T, const int* __restrict__ tags,
    float* __restrict__ Pmat, float* __restrict__ CC,
    float* __restrict__ scorearr) {
  const int blk = blockIdx.x, lane = threadIdx.x;
  if (blk >= NB * NC) {                         // ---- supervised score ----
    int b = blk - NB * NC;
    float local = 0.0f;
    for (int t = lane; t < SS; t += 64) {
      if (t == 0) {
        int tg = tags[b * SS];
        local += T[BOSR * NT + tg] + logits[(size_t)(b * SS) * 33 + tg];
      } else {
        int tg = tags[b * SS + t];
        int tp = tags[b * SS + t - 1];
        float m = mask[b * SS + t];
        local += m * (logits[(size_t)(b * SS + t) * 33 + tg] + T[tp * NT + tg]);
      }
    }
    float w = warp_sum64(local);
    if (lane == 0) scorearr[b] = w;
    return;
  }

  __shared__ unsigned short S[48][72];          // P bf16, stride 72 (2-way max)
  __shared__ float eeL[64][52];                 // exp(emissions), 16B-aligned rows
  __shared__ float mk[64];
  const int b = blk >> 4, c = blk & 15;
  const int q = lane >> 4, l15 = lane & 15;

  {                                             // zero S then identity
    unsigned long long* p = (unsigned long long*)&S[0][0];   // 864 qwords
    for (int i = lane; i < 864; i += 64) p[i] = 0ull;
  }
  __syncthreads();
  if (lane < NT) S[lane][lane] = 0x3F80;        // bf16(1.0)

  int t = c * 64 + 1 + lane;                    // this lane's step
  if (t < SS) {
    size_t rg = (size_t)b * SS + t;
    #pragma unroll
    for (int j = 0; j < 33; ++j) eeL[lane][j] = __expf(logits[rg * 33 + j]);
    eeL[lane][33] = __expf(bos[rg]);
    #pragma unroll
    for (int j = 34; j < 48; ++j) eeL[lane][j] = 0.0f;
    mk[lane] = mask[rg];
  } else {
    #pragma unroll
    for (int j = 0; j < 48; ++j) eeL[lane][j] = 0.0f;
    mk[lane] = 0.0f;
  }

  bf16x8 Af[3][2];                              // static A = expT^T frags
  const unsigned short* eta = bw + BW_ETA;
  #pragma unroll
  for (int mt = 0; mt < 3; ++mt)
    #pragma unroll
    for (int kt = 0; kt < 2; ++kt)
      Af[mt][kt] = *(const bf16x8*)(eta + (mt * 16 + l15) * 64 + kt * 32 + q * 8);

  float Clog = 0.0f;
  __syncthreads();

  for (int tt = 0; tt < 64; ++tt) {
    float mval = mk[tt];                        // broadcast read, wave-uniform
    if (mval > 0.5f) {
      bf16x8 Bf[2][3];
      #pragma unroll
      for (int kt = 0; kt < 2; ++kt)
        #pragma unroll
        for (int nt = 0; nt < 3; ++nt)
          Bf[kt][nt] = *(const bf16x8*)&S[nt * 16 + l15][kt * 32 + q * 8];
      f32x4 acc[3][3];
      f32x4 z4 = {0.f, 0.f, 0.f, 0.f};
      #pragma unroll
      for (int mt = 0; mt < 3; ++mt)
        #pragma unroll
        for (int nt = 0; nt < 3; ++nt) {
          acc[mt][nt] = __builtin_amdgcn_mfma_f32_16x16x32_bf16(
              Af[mt][0], Bf[0][nt], z4, 0, 0, 0);
          acc[mt][nt] = __builtin_amdgcn_mfma_f32_16x16x32_bf16(
              Af[mt][1], Bf[1][nt], acc[mt][nt], 0, 0, 0);
        }
      float r = rfl(acc[0][0][0]);              // D[0][0] = P_new[0][0] > 0
      float rin = __builtin_amdgcn_rcpf(r);
      float Cadd = __logf(r);
      #pragma unroll
      for (int mt = 0; mt < 3; ++mt) {
        f32x4 e4 = *(const f32x4*)&eeL[tt][mt * 16 + q * 4];
        e4 = e4 * rin;                          // combined col-scale * renorm
        #pragma unroll
        for (int nt = 0; nt < 3; ++nt) {
          f32x4 v = acc[mt][nt] * e4;
          unsigned long long pk =
              (unsigned long long)f2bf(v[0]) |
              ((unsigned long long)f2bf(v[1]) << 16) |
              ((unsigned long long)f2bf(v[2]) << 32) |
              ((unsigned long long)f2bf(v[3]) << 48);
          *(unsigned long long*)&S[nt * 16 + l15][mt * 16 + q * 4] = pk;
        }
      }
      Clog += Cadd;
      __syncthreads();                          // 1 wave: waitcnt + barrier
    }
  }

  __syncthreads();
  float* Pb = Pmat + (size_t)(b * NC + c) * (NP * NP);
  #pragma unroll
  for (int i = 0; i < 9; ++i) {                 // dump S -> f32 Pmat
    int flat = i * 64 + lane;                   // 0..575 float4 slots
    int n = flat / 12, qq = flat - n * 12;
    unsigned long long pk = *(unsigned long long*)&S[n][qq * 4];
    float4 o;
    o.x = bf2f((unsigned short)(pk));
    o.y = bf2f((unsigned short)(pk >> 16));
    o.z = bf2f((unsigned short)(pk >> 32));
    o.w = bf2f((unsigned short)(pk >> 48));
    *(float4*)&Pb[n * 48 + qq * 4] = o;
  }
  if (lane == 0) CC[b * NC + c] = Clog;
}

// ---------------- per-batch serial combine: Z_b ------------------------------
__global__ __launch_bounds__(64) void reduceZ(
    const float* __restrict__ logits, const float* __restrict__ bos,
    const float* __restrict__ T, const float* __restrict__ Pmat,
    const float* __restrict__ CC, float* __restrict__ Zarr) {
  __shared__ float shv[64];
  const int b = blockIdx.x, lane = threadIdx.x;
  float a0;
  if (lane < 33)       a0 = logits[(size_t)b * SS * 33 + lane] + T[BOSR * NT + lane];
  else if (lane == 33) a0 = bos[(size_t)b * SS] + T[BOSR * NT + 33];
  else                 a0 = -INFINITY;
  float K = rfl(a0);                            // lane0 finite
  float v = (lane < 48) ? __expf(a0 - K) : 0.0f;
  float C = K;
  for (int c = 0; c < NC; ++c) {
    shv[lane] = v;
    __syncthreads();
    float u = 0.0f;
    if (lane < 48) {
      const float* Pr = Pmat + (size_t)(b * NC + c) * (NP * NP) + lane * 48;
      #pragma unroll
      for (int qq = 0; qq < 12; ++qq) {
        float4 p4 = *(const float4*)(Pr + qq * 4);
        float4 v4 = *(const float4*)&shv[qq * 4];
        u = fmaf(p4.x, v4.x, u);
        u = fmaf(p4.y, v4.y, u);
        u = fmaf(p4.z, v4.z, u);
        u = fmaf(p4.w, v4.w, u);
      }
    }
    float r = rfl(u);                           // lane0: u > 0
    v = u * __builtin_amdgcn_rcpf(r);
    C += __logf(r) + CC[b * NC + c];
    __syncthreads();
  }
  float s = warp_sum64(v);
  if (lane == 0) Zarr[b] = C + __logf(s);
}

// ---------------- final: loss = sum_b (Z_b - score_b) ------------------------
__global__ void finalk(const float* __restrict__ Zarr,
                       const float* __restrict__ sc, float* __restrict__ out) {
  float x = Zarr[threadIdx.x] - sc[threadIdx.x];
  float s = warp_sum64(x);
  if (threadIdx.x == 0) out[0] = s;
}

extern "C" void kernel_launch(void* const* d_in, const int* in_sizes, int n_in,
                              void* d_out, int out_size, void* d_ws, size_t ws_size,
                              hipStream_t stream) {
  const float* em   = (const float*)d_in[0];
  const int*   tags = (const int*)d_in[1];
  const float* mask = (const float*)d_in[2];
  const float* W    = (const float*)d_in[3];
  const float* bias = (const float*)d_in[4];
  const float* T    = (const float*)d_in[5];

  float* out = (float*)d_out;
  float* ws  = (float*)d_ws;
  float* bos   = ws + WS_BOS;
  float* Pmat  = ws + WS_PMAT;
  float* CC    = ws + WS_CC;
  float* Zarr  = ws + WS_Z;
  float* score = ws + WS_SC;
  unsigned short* bw = (unsigned short*)(ws + WS_BF16);
  float* logits = out + 1;                      // d_out = [loss, logits(B,S,33)]

  hipLaunchKernelGGL(prep, dim3(204), dim3(256), 0, stream, W, T, bw);
  hipLaunchKernelGGL(gemm_mfma, dim3(NB * SS / 128), dim3(256), 0, stream,
                     em, bw, bias, logits, bos);
  hipLaunchKernelGGL(chains_mat, dim3(NB * NC + NB), dim3(64), 0, stream,
                     logits, bos, bw, mask, T, tags, Pmat, CC, score);
  hipLaunchKernelGGL(reduceZ, dim3(NB), dim3(64), 0, stream,
                     logits, bos, T, Pmat, CC, Zarr);
  hipLaunchKernelGGL(finalk, dim3(1), dim3(64), 0, stream, Zarr, score, out);
}